// Round 3
// baseline (223.612 us; speedup 1.0000x reference)
//
#include <hip/hip_runtime.h>
#include <hip/hip_bf16.h>

#define EMB 16
#define HID 64
#define NE  8
#define TPG 64   // tokens per wave-group (one router lane per token)
#define NWAVE 8  // waves per block

typedef float f32x4 __attribute__((ext_vector_type(4)));
typedef short s16x4 __attribute__((ext_vector_type(4)));

// fp32 -> bf16, round-to-nearest-even (no NaN in this workload)
__device__ __forceinline__ short f2bf(float f) {
    union { float f; unsigned u; } v; v.f = f;
    unsigned u = v.u;
    u += 0x7FFFu + ((u >> 16) & 1u);
    return (short)(u >> 16);
}

__global__ __launch_bounds__(512, 4)
void moe_fused(const float* __restrict__ x, const float* __restrict__ Wr,
               const float* __restrict__ br, const float* __restrict__ W1,
               const float* __restrict__ b1, const float* __restrict__ W2,
               const float* __restrict__ b2, float* __restrict__ out,
               int n_tokens)
{
    // Weights in LDS, one copy shared by 8 waves. ~51 KB total -> 2 blocks/CU,
    // 16 waves/CU (VGPR=128 cap).
    __shared__ __align__(16) s16x4 w1lds[NE * 4 * 64];      // 16 KB: [e][n][lane]
    __shared__ __align__(16) s16x4 w2lds[NE * 4 * 64];      // 16 KB: [e][q][lane]
    __shared__ __align__(16) float b1_lds[NE * HID];        // 2 KB
    __shared__ __align__(16) float wr_lds[EMB * NE];
    __shared__ __align__(16) float br_lds[NE];
    __shared__ __align__(16) float b2_lds[NE * EMB];
    __shared__ __align__(16) float wt_lds[NWAVE * NE * TPG]; // 16 KB, wave-private gates

    const int tid = threadIdx.x;

    // ---- one-time per block: weights fp32->bf16 in per-lane fragment order ----
    // w1lds[(e*4+n)*64 + lane(cg,col)][j] = W1[e][4cg+j][16n+col]   (G1 A-frag, swapped)
    // w2lds[(e*4+q)*64 + lane(cg,col)][j] = W2[e][16q+4cg+j][col]   (G2 A-frag, swapped)
    for (int s = tid; s < NE * 4 * 64; s += 512) {
        const int e = s >> 8, nq = (s >> 6) & 3, l = s & 63;
        const int cc = l & 15, gg = (l >> 4) & 3;
        s16x4 t1, t2;
#pragma unroll
        for (int j = 0; j < 4; ++j) {
            t1[j] = f2bf(W1[(e * EMB + 4 * gg + j) * HID + 16 * nq + cc]);
            t2[j] = f2bf(W2[(e * HID + 16 * nq + 4 * gg + j) * EMB + cc]);
        }
        w1lds[s] = t1;
        w2lds[s] = t2;
    }
    for (int i = tid; i < NE * HID; i += 512) b1_lds[i] = b1[i];
    if (tid < EMB * NE) wr_lds[tid] = Wr[tid];
    if (tid < NE * EMB) b2_lds[tid] = b2[tid];
    if (tid < NE) br_lds[tid] = br[tid];
    __syncthreads();

    const int lane = tid & 63;
    const int wid  = tid >> 6;
    const int col  = lane & 15;
    const int cg   = lane >> 4;
    float* wt = wt_lds + wid * (NE * TPG);

    const int n_groups = n_tokens / TPG;
    const int gw = blockIdx.x * NWAVE + wid;
    const int nw = gridDim.x * NWAVE;

    for (int g = gw; g < n_groups; g += nw) {
        const int tok0 = g * TPG;

        // ---------------- router: lane owns token tok0+lane (fp32, fp64 rescue) ----------------
        {
            float xk[EMB];
            const f32x4* xp = (const f32x4*)(x + (tok0 + lane) * EMB);
#pragma unroll
            for (int q4 = 0; q4 < 4; ++q4) {
                f32x4 v = xp[q4];
#pragma unroll
                for (int j = 0; j < 4; ++j) xk[q4 * 4 + j] = v[j];
            }
            float lg[NE];
#pragma unroll
            for (int e = 0; e < NE; ++e) lg[e] = br_lds[e];
#pragma unroll
            for (int k = 0; k < EMB; ++k) {
                const float xv = xk[k];
#pragma unroll
                for (int e = 0; e < NE; ++e) lg[e] = fmaf(xv, wr_lds[k * NE + e], lg[e]);
            }
            float m1 = -1e30f, m2 = -1e30f, m3 = -1e30f;
#pragma unroll
            for (int e = 0; e < NE; ++e) {
                const float v   = lg[e];
                const float hi  = fmaxf(m1, v), lo  = fminf(m1, v);
                const float hi2 = fmaxf(m2, lo), lo2 = fminf(m2, lo);
                m1 = hi; m2 = hi2; m3 = fmaxf(m3, lo2);
            }
            bool sel[NE];
            if (m2 - m3 < 1e-4f) {
                // near-tie at the top-2 boundary: exact recompute (rare path)
                double dl[NE];
#pragma unroll
                for (int e = 0; e < NE; ++e) dl[e] = (double)br_lds[e];
#pragma unroll
                for (int k = 0; k < EMB; ++k) {
                    const double xv = (double)xk[k];
#pragma unroll
                    for (int e = 0; e < NE; ++e)
                        dl[e] = fma(xv, (double)wr_lds[k * NE + e], dl[e]);
                }
                double M1 = -1e300, M2 = -1e300;
#pragma unroll
                for (int e = 0; e < NE; ++e) {
                    const double v  = dl[e];
                    const double hi = fmax(M1, v);
                    M2 = fmax(M2, fmin(M1, v));
                    M1 = hi;
                }
#pragma unroll
                for (int e = 0; e < NE; ++e) sel[e] = (dl[e] >= M2);
            } else {
#pragma unroll
                for (int e = 0; e < NE; ++e) sel[e] = (lg[e] >= m2);
            }
            float w[NE], s = 0.f;
#pragma unroll
            for (int e = 0; e < NE; ++e) { w[e] = __expf(lg[e] - m1); s += w[e]; }
            const float inv = 1.0f / s;
#pragma unroll
            for (int e = 0; e < NE; ++e)
                wt[e * TPG + lane] = sel[e] ? w[e] * inv : 0.0f;
        }

        // ---------------- B-fragments of x for the 4 token tiles ----------------
        s16x4 xb[4];
#pragma unroll
        for (int T = 0; T < 4; ++T) {
            f32x4 xv = *(const f32x4*)(x + (tok0 + 16 * T + col) * EMB + 4 * cg);
#pragma unroll
            for (int j = 0; j < 4; ++j) xb[T][j] = f2bf(xv[j]);
        }

        // oaccT[T]: eo^T accumulator, C-chained across q AND experts.
        // b2acc[T]: Sum_e w_e * b2[e][emb] (bias must not pass through relu-weighting).
        f32x4 oaccT[4], b2acc[4];
#pragma unroll
        for (int T = 0; T < 4; ++T) {
            oaccT[T] = (f32x4){0.f, 0.f, 0.f, 0.f};
            b2acc[T] = (f32x4){0.f, 0.f, 0.f, 0.f};
        }

        // ---------------- expert loop (streamed from LDS, low reg pressure) ----------------
#pragma unroll 1
        for (int e = 0; e < NE; ++e) {
            s16x4 a1[4], a2[4];
            f32x4 b1c[4];
#pragma unroll
            for (int n = 0; n < 4; ++n) {
                a1[n]  = w1lds[(e * 4 + n) * 64 + lane];
                a2[n]  = w2lds[(e * 4 + n) * 64 + lane];
                b1c[n] = *(const f32x4*)(b1_lds + e * HID + 16 * n + 4 * cg);
            }
            const f32x4 b2c = *(const f32x4*)(b2_lds + e * EMB + 4 * cg);
            const float* wte = wt + e * TPG;

#pragma unroll
            for (int T = 0; T < 4; ++T) {
                // gate weight for THIS lane's token (16T+col): one broadcast LDS read
                const float wv = wte[16 * T + col];
                // G1: h^T tile n, C-in = b1  (lane: h[tok=col][hid=16n+4cg+r])
                f32x4 h[4];
#pragma unroll
                for (int n = 0; n < 4; ++n)
                    h[n] = __builtin_amdgcn_mfma_f32_16x16x16bf16_1k(a1[n], xb[T], b1c[n], 0, 0, 0);
                // G2 swapped: eoT[emb][tok] = W2^T x (w*relu(h)); A=w2 frag, B=weighted relu(h).
                // C chains across q and across experts -> no merge FMAs, no eo regs.
#pragma unroll
                for (int q = 0; q < 4; ++q) {
                    s16x4 b;
#pragma unroll
                    for (int j = 0; j < 4; ++j) b[j] = f2bf(fmaxf(h[q][j], 0.f) * wv);
                    oaccT[T] = __builtin_amdgcn_mfma_f32_16x16x16bf16_1k(a2[q], b, oaccT[T], 0, 0, 0);
                }
                // bias term: Sum_e w_e * b2[e][4cg+r]
#pragma unroll
                for (int r = 0; r < 4; ++r)
                    b2acc[T][r] = fmaf(wv, b2c[r], b2acc[T][r]);
            }
        }

        // ---------------- store: lane owns token 16T+col, emb 4cg..4cg+3 -> dwordx4 ----------------
#pragma unroll
        for (int T = 0; T < 4; ++T) {
            f32x4 o;
#pragma unroll
            for (int r = 0; r < 4; ++r) o[r] = oaccT[T][r] + b2acc[T][r];
            *(f32x4*)(out + (tok0 + 16 * T + col) * EMB + 4 * cg) = o;
        }
    }
}

extern "C" void kernel_launch(void* const* d_in, const int* in_sizes, int n_in,
                              void* d_out, int out_size, void* d_ws, size_t ws_size,
                              hipStream_t stream) {
    const float* x  = (const float*)d_in[0];
    const float* Wr = (const float*)d_in[1];
    const float* br = (const float*)d_in[2];
    const float* W1 = (const float*)d_in[3];
    const float* b1 = (const float*)d_in[4];
    const float* W2 = (const float*)d_in[5];
    const float* b2 = (const float*)d_in[6];
    float* out = (float*)d_out;

    const int n_tokens = in_sizes[0] / EMB;   // 64*4096 = 262144
    // 512 blocks x 8 waves = 4096 waves = one 64-token group per wave.
    // 51 KB LDS + 128 VGPR -> 2 blocks/CU = 16 waves/CU (50% occupancy).
    hipLaunchKernelGGL(moe_fused, dim3(512), dim3(512), 0, stream,
                       x, Wr, br, W1, b1, W2, b2, out, n_tokens);
}

// Round 4
// 127.931 us; speedup vs baseline: 1.7479x; 1.7479x over previous
//
#include <hip/hip_runtime.h>
#include <hip/hip_bf16.h>

#define EMB 16
#define HID 64
#define NE  8
#define TPG 64   // tokens per wave-group (one router lane per token)
#define NWAVE 8  // waves per block

typedef float f32x4 __attribute__((ext_vector_type(4)));
typedef short s16x4 __attribute__((ext_vector_type(4)));

// fp32 -> bf16, round-to-nearest-even (no NaN in this workload)
__device__ __forceinline__ short f2bf(float f) {
    union { float f; unsigned u; } v; v.f = f;
    unsigned u = v.u;
    u += 0x7FFFu + ((u >> 16) & 1u);
    return (short)(u >> 16);
}

// launch_bounds(512,2): round-3's (512,4) let the compiler clamp to 64 VGPRs
// (3 LDS-fit blocks -> 6 waves/EU target) and spill ~500 MB of scratch.
// 2 waves/EU -> 256-VGPR cap, live set ~130 regs fits, 2 blocks/CU = 16 waves/CU.
__global__ __launch_bounds__(512, 2)
void moe_fused(const float* __restrict__ x, const float* __restrict__ Wr,
               const float* __restrict__ br, const float* __restrict__ W1,
               const float* __restrict__ b1, const float* __restrict__ W2,
               const float* __restrict__ b2, float* __restrict__ out,
               int n_tokens)
{
    __shared__ __align__(16) s16x4 w1lds[NE * 4 * 64];      // 16 KB: [e][n][lane]
    __shared__ __align__(16) s16x4 w2lds[NE * 4 * 64];      // 16 KB: [e][q][lane]
    __shared__ __align__(16) float b1_lds[NE * HID];        // 2 KB
    __shared__ __align__(16) float wr_lds[EMB * NE];
    __shared__ __align__(16) float br_lds[NE];
    __shared__ __align__(16) float b2_lds[NE * EMB];
    __shared__ __align__(16) float wt_lds[NWAVE * NE * TPG]; // 16 KB, wave-private gates

    const int tid = threadIdx.x;

    // ---- one-time per block: weights fp32->bf16 in per-lane fragment order ----
    // w1lds[(e*4+n)*64 + lane(cg,col)][j] = W1[e][4cg+j][16n+col]   (G1 A-frag, swapped)
    // w2lds[(e*4+q)*64 + lane(cg,col)][j] = W2[e][16q+4cg+j][col]   (G2 A-frag, swapped)
    for (int s = tid; s < NE * 4 * 64; s += 512) {
        const int e = s >> 8, nq = (s >> 6) & 3, l = s & 63;
        const int cc = l & 15, gg = (l >> 4) & 3;
        s16x4 t1, t2;
#pragma unroll
        for (int j = 0; j < 4; ++j) {
            t1[j] = f2bf(W1[(e * EMB + 4 * gg + j) * HID + 16 * nq + cc]);
            t2[j] = f2bf(W2[(e * HID + 16 * nq + 4 * gg + j) * EMB + cc]);
        }
        w1lds[s] = t1;
        w2lds[s] = t2;
    }
    for (int i = tid; i < NE * HID; i += 512) b1_lds[i] = b1[i];
    if (tid < EMB * NE) wr_lds[tid] = Wr[tid];
    if (tid < NE * EMB) b2_lds[tid] = b2[tid];
    if (tid < NE) br_lds[tid] = br[tid];
    __syncthreads();

    const int lane = tid & 63;
    const int wid  = tid >> 6;
    const int col  = lane & 15;
    const int cg   = lane >> 4;
    float* wt = wt_lds + wid * (NE * TPG);

    const int n_groups = n_tokens / TPG;
    const int gw = blockIdx.x * NWAVE + wid;
    const int nw = gridDim.x * NWAVE;

    for (int g = gw; g < n_groups; g += nw) {
        const int tok0 = g * TPG;

        // ---------------- router: lane owns token tok0+lane (fp32, fp64 rescue) ----------------
        {
            float xk[EMB];
            const f32x4* xp = (const f32x4*)(x + (tok0 + lane) * EMB);
#pragma unroll
            for (int q4 = 0; q4 < 4; ++q4) {
                f32x4 v = xp[q4];
#pragma unroll
                for (int j = 0; j < 4; ++j) xk[q4 * 4 + j] = v[j];
            }
            float lg[NE];
#pragma unroll
            for (int e = 0; e < NE; ++e) lg[e] = br_lds[e];
#pragma unroll
            for (int k = 0; k < EMB; ++k) {
                const float xv = xk[k];
#pragma unroll
                for (int e = 0; e < NE; ++e) lg[e] = fmaf(xv, wr_lds[k * NE + e], lg[e]);
            }
            float m1 = -1e30f, m2 = -1e30f, m3 = -1e30f;
#pragma unroll
            for (int e = 0; e < NE; ++e) {
                const float v   = lg[e];
                const float hi  = fmaxf(m1, v), lo  = fminf(m1, v);
                const float hi2 = fmaxf(m2, lo), lo2 = fminf(m2, lo);
                m1 = hi; m2 = hi2; m3 = fmaxf(m3, lo2);
            }
            bool sel[NE];
            if (m2 - m3 < 1e-4f) {
                // near-tie at the top-2 boundary: exact recompute (rare path)
                double dl[NE];
#pragma unroll
                for (int e = 0; e < NE; ++e) dl[e] = (double)br_lds[e];
#pragma unroll
                for (int k = 0; k < EMB; ++k) {
                    const double xv = (double)xk[k];
#pragma unroll
                    for (int e = 0; e < NE; ++e)
                        dl[e] = fma(xv, (double)wr_lds[k * NE + e], dl[e]);
                }
                double M1 = -1e300, M2 = -1e300;
#pragma unroll
                for (int e = 0; e < NE; ++e) {
                    const double v  = dl[e];
                    const double hi = fmax(M1, v);
                    M2 = fmax(M2, fmin(M1, v));
                    M1 = hi;
                }
#pragma unroll
                for (int e = 0; e < NE; ++e) sel[e] = (dl[e] >= M2);
            } else {
#pragma unroll
                for (int e = 0; e < NE; ++e) sel[e] = (lg[e] >= m2);
            }
            float w[NE], s = 0.f;
#pragma unroll
            for (int e = 0; e < NE; ++e) { w[e] = __expf(lg[e] - m1); s += w[e]; }
            const float inv = 1.0f / s;
#pragma unroll
            for (int e = 0; e < NE; ++e)
                wt[e * TPG + lane] = sel[e] ? w[e] * inv : 0.0f;
        }

        // ---------------- B-fragments of x for the 4 token tiles ----------------
        s16x4 xb[4];
#pragma unroll
        for (int T = 0; T < 4; ++T) {
            f32x4 xv = *(const f32x4*)(x + (tok0 + 16 * T + col) * EMB + 4 * cg);
#pragma unroll
            for (int j = 0; j < 4; ++j) xb[T][j] = f2bf(xv[j]);
        }

        // oaccT[T]: eo^T accumulator, C-chained across q AND experts.
        // b2acc[T]: Sum_e w_e * b2[e][emb] (bias must not pass through relu-weighting).
        f32x4 oaccT[4], b2acc[4];
#pragma unroll
        for (int T = 0; T < 4; ++T) {
            oaccT[T] = (f32x4){0.f, 0.f, 0.f, 0.f};
            b2acc[T] = (f32x4){0.f, 0.f, 0.f, 0.f};
        }

        // ---------------- expert loop (streamed from LDS, low reg pressure) ----------------
#pragma unroll 1
        for (int e = 0; e < NE; ++e) {
            s16x4 a1[4], a2[4];
            f32x4 b1c[4];
#pragma unroll
            for (int n = 0; n < 4; ++n) {
                a1[n]  = w1lds[(e * 4 + n) * 64 + lane];
                a2[n]  = w2lds[(e * 4 + n) * 64 + lane];
                b1c[n] = *(const f32x4*)(b1_lds + e * HID + 16 * n + 4 * cg);
            }
            const f32x4 b2c = *(const f32x4*)(b2_lds + e * EMB + 4 * cg);
            const float* wte = wt + e * TPG;

#pragma unroll
            for (int T = 0; T < 4; ++T) {
                // gate weight for THIS lane's token (16T+col): one broadcast LDS read
                const float wv = wte[16 * T + col];
                // G1: h^T tile n, C-in = b1  (lane: h[tok=col][hid=16n+4cg+r])
                f32x4 h[4];
#pragma unroll
                for (int n = 0; n < 4; ++n)
                    h[n] = __builtin_amdgcn_mfma_f32_16x16x16bf16_1k(a1[n], xb[T], b1c[n], 0, 0, 0);
                // G2 swapped: eoT[emb][tok] = W2^T x (w*relu(h)); A=w2 frag, B=weighted relu(h).
                // C chains across q and across experts -> no merge FMAs, no eo regs.
#pragma unroll
                for (int q = 0; q < 4; ++q) {
                    s16x4 b;
#pragma unroll
                    for (int j = 0; j < 4; ++j) b[j] = f2bf(fmaxf(h[q][j], 0.f) * wv);
                    oaccT[T] = __builtin_amdgcn_mfma_f32_16x16x16bf16_1k(a2[q], b, oaccT[T], 0, 0, 0);
                }
                // bias term: Sum_e w_e * b2[e][4cg+r]
#pragma unroll
                for (int r = 0; r < 4; ++r)
                    b2acc[T][r] = fmaf(wv, b2c[r], b2acc[T][r]);
            }
        }

        // ---------------- store: lane owns token 16T+col, emb 4cg..4cg+3 -> dwordx4 ----------------
#pragma unroll
        for (int T = 0; T < 4; ++T) {
            f32x4 o;
#pragma unroll
            for (int r = 0; r < 4; ++r) o[r] = oaccT[T][r] + b2acc[T][r];
            *(f32x4*)(out + (tok0 + 16 * T + col) * EMB + 4 * cg) = o;
        }
    }
}

extern "C" void kernel_launch(void* const* d_in, const int* in_sizes, int n_in,
                              void* d_out, int out_size, void* d_ws, size_t ws_size,
                              hipStream_t stream) {
    const float* x  = (const float*)d_in[0];
    const float* Wr = (const float*)d_in[1];
    const float* br = (const float*)d_in[2];
    const float* W1 = (const float*)d_in[3];
    const float* b1 = (const float*)d_in[4];
    const float* W2 = (const float*)d_in[5];
    const float* b2 = (const float*)d_in[6];
    float* out = (float*)d_out;

    const int n_tokens = in_sizes[0] / EMB;   // 64*4096 = 262144
    // 512 blocks x 8 waves = 4096 waves = one 64-token group per wave.
    hipLaunchKernelGGL(moe_fused, dim3(512), dim3(512), 0, stream,
                       x, Wr, br, W1, b1, W2, b2, out, n_tokens);
}

// Round 5
// 126.129 us; speedup vs baseline: 1.7729x; 1.0143x over previous
//
#include <hip/hip_runtime.h>
#include <hip/hip_bf16.h>

#define EMB 16
#define HID 64
#define NE  8
#define TPG 64   // tokens per wave-group (one router lane per token)
#define NWAVE 8  // waves per block

typedef float f32x4 __attribute__((ext_vector_type(4)));
typedef short s16x4 __attribute__((ext_vector_type(4)));

// fp32 -> bf16, round-to-nearest-even (no NaN in this workload)
__device__ __forceinline__ short f2bf(float f) {
    union { float f; unsigned u; } v; v.f = f;
    unsigned u = v.u;
    u += 0x7FFFu + ((u >> 16) & 1u);
    return (short)(u >> 16);
}

__global__ __launch_bounds__(512, 2)
void moe_fused(const float* __restrict__ x, const float* __restrict__ Wr,
               const float* __restrict__ br, const float* __restrict__ W1,
               const float* __restrict__ b1, const float* __restrict__ W2,
               const float* __restrict__ b2, float* __restrict__ out,
               int n_tokens)
{
    __shared__ __align__(16) s16x4 w1lds[NE * 4 * 64];      // 16 KB: [e][n][lane]
    __shared__ __align__(16) s16x4 w2lds[NE * 4 * 64];      // 16 KB: [e][q][lane]
    __shared__ __align__(16) float b1_lds[NE * HID];        // 2 KB
    __shared__ __align__(16) float wr_lds[EMB * NE];
    __shared__ __align__(16) float br_lds[NE];
    __shared__ __align__(16) float b2_lds[NE * EMB];
    __shared__ __align__(16) float wt_lds[NWAVE * NE * TPG]; // 16 KB, wave-private gates

    const int tid = threadIdx.x;

    // ---- one-time per block: weights fp32->bf16 in per-lane fragment order ----
    // w1lds[(e*4+n)*64 + lane(cg,col)][j] = W1[e][4cg+j][16n+col]   (G1 A-frag, swapped)
    // w2lds[(e*4+q)*64 + lane(cg,col)][j] = W2[e][16q+4cg+j][col]   (G2 A-frag, swapped)
    for (int s = tid; s < NE * 4 * 64; s += 512) {
        const int e = s >> 8, nq = (s >> 6) & 3, l = s & 63;
        const int cc = l & 15, gg = (l >> 4) & 3;
        s16x4 t1, t2;
#pragma unroll
        for (int j = 0; j < 4; ++j) {
            t1[j] = f2bf(W1[(e * EMB + 4 * gg + j) * HID + 16 * nq + cc]);
            t2[j] = f2bf(W2[(e * HID + 16 * nq + 4 * gg + j) * EMB + cc]);
        }
        w1lds[s] = t1;
        w2lds[s] = t2;
    }
    for (int i = tid; i < NE * HID; i += 512) b1_lds[i] = b1[i];
    if (tid < EMB * NE) wr_lds[tid] = Wr[tid];
    if (tid < NE * EMB) b2_lds[tid] = b2[tid];
    if (tid < NE) br_lds[tid] = br[tid];
    __syncthreads();

    const int lane = tid & 63;
    const int wid  = tid >> 6;
    const int col  = lane & 15;
    const int cg   = lane >> 4;
    float* wt = wt_lds + wid * (NE * TPG);

    const int n_groups = n_tokens / TPG;
    const int gw = blockIdx.x * NWAVE + wid;
    const int nw = gridDim.x * NWAVE;

    for (int g = gw; g < n_groups; g += nw) {
        const int tok0 = g * TPG;

        // ---------------- router: lane owns token tok0+lane (fp32, fp64 rescue) ----------------
        {
            float xk[EMB];
            const f32x4* xp = (const f32x4*)(x + (tok0 + lane) * EMB);
#pragma unroll
            for (int q4 = 0; q4 < 4; ++q4) {
                f32x4 v = xp[q4];
#pragma unroll
                for (int j = 0; j < 4; ++j) xk[q4 * 4 + j] = v[j];
            }
            float lg[NE];
#pragma unroll
            for (int e = 0; e < NE; ++e) lg[e] = br_lds[e];
#pragma unroll
            for (int k = 0; k < EMB; ++k) {
                const float xv = xk[k];
#pragma unroll
                for (int e = 0; e < NE; ++e) lg[e] = fmaf(xv, wr_lds[k * NE + e], lg[e]);
            }
            float m1 = -1e30f, m2 = -1e30f, m3 = -1e30f;
#pragma unroll
            for (int e = 0; e < NE; ++e) {
                const float v   = lg[e];
                const float hi  = fmaxf(m1, v), lo  = fminf(m1, v);
                const float hi2 = fmaxf(m2, lo), lo2 = fminf(m2, lo);
                m1 = hi; m2 = hi2; m3 = fmaxf(m3, lo2);
            }
            bool sel[NE];
            if (m2 - m3 < 1e-4f) {
                // near-tie at the top-2 boundary: exact recompute (rare path)
                double dl[NE];
#pragma unroll
                for (int e = 0; e < NE; ++e) dl[e] = (double)br_lds[e];
#pragma unroll
                for (int k = 0; k < EMB; ++k) {
                    const double xv = (double)xk[k];
#pragma unroll
                    for (int e = 0; e < NE; ++e)
                        dl[e] = fma(xv, (double)wr_lds[k * NE + e], dl[e]);
                }
                double M1 = -1e300, M2 = -1e300;
#pragma unroll
                for (int e = 0; e < NE; ++e) {
                    const double v  = dl[e];
                    const double hi = fmax(M1, v);
                    M2 = fmax(M2, fmin(M1, v));
                    M1 = hi;
                }
#pragma unroll
                for (int e = 0; e < NE; ++e) sel[e] = (dl[e] >= M2);
            } else {
#pragma unroll
                for (int e = 0; e < NE; ++e) sel[e] = (lg[e] >= m2);
            }
            float w[NE], s = 0.f;
#pragma unroll
            for (int e = 0; e < NE; ++e) { w[e] = __expf(lg[e] - m1); s += w[e]; }
            const float inv = 1.0f / s;
#pragma unroll
            for (int e = 0; e < NE; ++e)
                wt[e * TPG + lane] = sel[e] ? w[e] * inv : 0.0f;
        }

        // ---------------- one 16-token tile at a time: minimal live set, no spill ----------------
#pragma unroll 1
        for (int T = 0; T < 4; ++T) {
            const int tok = tok0 + 16 * T + col;
            // G1 B-frag: B[k=4cg+j][tok=col] = x[tok][4cg+j]
            const f32x4 xv = *(const f32x4*)(x + tok * EMB + 4 * cg);
            s16x4 xb;
#pragma unroll
            for (int j = 0; j < 4; ++j) xb[j] = f2bf(xv[j]);

            // oacc init = Sum_e w_e * b2[e][4cg+r]  (bias bypasses relu-weighting;
            // folding it here removes the second accumulator array entirely)
            f32x4 oacc = {0.f, 0.f, 0.f, 0.f};
#pragma unroll
            for (int e = 0; e < NE; ++e) {
                const float wv  = wt[e * TPG + 16 * T + col];
                const f32x4 b2c = *(const f32x4*)(b2_lds + e * EMB + 4 * cg);
#pragma unroll
                for (int r = 0; r < 4; ++r) oacc[r] = fmaf(wv, b2c[r], oacc[r]);
            }

            // expert loop: fragments re-read from LDS each (T,e); live regs ~60
#pragma unroll 1
            for (int e = 0; e < NE; ++e) {
                const float wv = wt[e * TPG + 16 * T + col];
                // G1: h^T tile n (lane: h[tok=col][hid=16n+4cg+r]), C-in = b1
                f32x4 h[4];
#pragma unroll
                for (int n = 0; n < 4; ++n) {
                    const s16x4 a1  = w1lds[(e * 4 + n) * 64 + lane];
                    const f32x4 b1c = *(const f32x4*)(b1_lds + e * HID + 16 * n + 4 * cg);
                    h[n] = __builtin_amdgcn_mfma_f32_16x16x16bf16_1k(a1, xb, b1c, 0, 0, 0);
                }
                // G2 swapped: eoT[emb][tok]; A = W2^T frag, B = w*relu(h); C chains q AND e
#pragma unroll
                for (int q = 0; q < 4; ++q) {
                    const s16x4 a2 = w2lds[(e * 4 + q) * 64 + lane];
                    s16x4 b;
#pragma unroll
                    for (int j = 0; j < 4; ++j) b[j] = f2bf(fmaxf(h[q][j], 0.f) * wv);
                    oacc = __builtin_amdgcn_mfma_f32_16x16x16bf16_1k(a2, b, oacc, 0, 0, 0);
                }
            }

            // store: lane owns token 16T+col, emb 4cg..4cg+3 -> nontemporal dwordx4
            __builtin_nontemporal_store(oacc, (f32x4*)(out + tok * EMB + 4 * cg));
        }
    }
}

extern "C" void kernel_launch(void* const* d_in, const int* in_sizes, int n_in,
                              void* d_out, int out_size, void* d_ws, size_t ws_size,
                              hipStream_t stream) {
    const float* x  = (const float*)d_in[0];
    const float* Wr = (const float*)d_in[1];
    const float* br = (const float*)d_in[2];
    const float* W1 = (const float*)d_in[3];
    const float* b1 = (const float*)d_in[4];
    const float* W2 = (const float*)d_in[5];
    const float* b2 = (const float*)d_in[6];
    float* out = (float*)d_out;

    const int n_tokens = in_sizes[0] / EMB;   // 64*4096 = 262144
    // 512 blocks x 8 waves = 4096 waves = one 64-token group per wave.
    hipLaunchKernelGGL(moe_fused, dim3(512), dim3(512), 0, stream,
                       x, Wr, br, W1, b1, W2, b2, out, n_tokens);
}

// Round 6
// 121.091 us; speedup vs baseline: 1.8466x; 1.0416x over previous
//
#include <hip/hip_runtime.h>
#include <hip/hip_bf16.h>

#define EMB 16
#define HID 64
#define NE  8
#define TPG 64   // tokens per wave-group

typedef float f32x4 __attribute__((ext_vector_type(4)));
typedef short s16x4 __attribute__((ext_vector_type(4)));

// fp32 -> bf16, round-to-nearest-even (no NaN in this workload)
__device__ __forceinline__ short f2bf(float f) {
    union { float f; unsigned u; } v; v.f = f;
    unsigned u = v.u;
    u += 0x7FFFu + ((u >> 16) & 1u);
    return (short)(u >> 16);
}

// ============================================================================
// Kernel 1: router only. One thread per token. Writes gates[t][e] (8 fp32).
// Isolated so its register peak (xk[16] + fp64 rescue) cannot force spills
// into the MFMA kernel (rounds 2-5 all showed 130-500 MB of scratch writeback).
// ============================================================================
__global__ void router_k(const float* __restrict__ x, const float* __restrict__ Wr,
                         const float* __restrict__ br, float* __restrict__ gates,
                         int n_tokens)
{
    __shared__ float wr_lds[EMB * NE];
    __shared__ float br_lds[NE];
    const int tid = threadIdx.x;
    if (tid < EMB * NE) wr_lds[tid] = Wr[tid];
    if (tid < NE) br_lds[tid] = br[tid];
    __syncthreads();

    for (int t = blockIdx.x * blockDim.x + tid; t < n_tokens; t += gridDim.x * blockDim.x) {
        float xk[EMB];
        const f32x4* xp = (const f32x4*)(x + (size_t)t * EMB);
#pragma unroll
        for (int q4 = 0; q4 < 4; ++q4) {
            f32x4 v = xp[q4];
#pragma unroll
            for (int j = 0; j < 4; ++j) xk[q4 * 4 + j] = v[j];
        }
        float lg[NE];
#pragma unroll
        for (int e = 0; e < NE; ++e) lg[e] = br_lds[e];
#pragma unroll
        for (int k = 0; k < EMB; ++k) {
            const float xv = xk[k];
#pragma unroll
            for (int e = 0; e < NE; ++e) lg[e] = fmaf(xv, wr_lds[k * NE + e], lg[e]);
        }
        // top-3 scan (m3 only gates the fp64 rescue)
        float m1 = -1e30f, m2 = -1e30f, m3 = -1e30f;
#pragma unroll
        for (int e = 0; e < NE; ++e) {
            const float v   = lg[e];
            const float hi  = fmaxf(m1, v), lo  = fminf(m1, v);
            const float hi2 = fmaxf(m2, lo), lo2 = fminf(m2, lo);
            m1 = hi; m2 = hi2; m3 = fmaxf(m3, lo2);
        }
        bool sel[NE];
        if (m2 - m3 < 1e-4f) {
            // near-tie at the top-2 boundary: exact recompute (rare path)
            double dl[NE];
#pragma unroll
            for (int e = 0; e < NE; ++e) dl[e] = (double)br_lds[e];
#pragma unroll
            for (int k = 0; k < EMB; ++k) {
                const double xv = (double)xk[k];
#pragma unroll
                for (int e = 0; e < NE; ++e)
                    dl[e] = fma(xv, (double)wr_lds[k * NE + e], dl[e]);
            }
            double M1 = -1e300, M2 = -1e300;
#pragma unroll
            for (int e = 0; e < NE; ++e) {
                const double v  = dl[e];
                const double hi = fmax(M1, v);
                M2 = fmax(M2, fmin(M1, v));
                M1 = hi;
            }
#pragma unroll
            for (int e = 0; e < NE; ++e) sel[e] = (dl[e] >= M2);
        } else {
#pragma unroll
            for (int e = 0; e < NE; ++e) sel[e] = (lg[e] >= m2);
        }
        float w[NE], s = 0.f;
#pragma unroll
        for (int e = 0; e < NE; ++e) { w[e] = __expf(lg[e] - m1); s += w[e]; }
        const float inv = 1.0f / s;
        f32x4 g0, g1;
#pragma unroll
        for (int e = 0; e < 4; ++e) g0[e] = sel[e] ? w[e] * inv : 0.0f;
#pragma unroll
        for (int e = 4; e < 8; ++e) g1[e - 4] = sel[e] ? w[e] * inv : 0.0f;
        f32x4* gp = (f32x4*)(gates + (size_t)t * NE);
        gp[0] = g0;   // wave writes 2 KB contiguous
        gp[1] = g1;
    }
}

// ============================================================================
// Kernel 2: MoE compute only. No router code -> tiny, regular register profile.
// Per wave: one 64-token group, 4 tiles of 16 tokens, dense 8-expert MFMA chain.
// ============================================================================
__global__ void moe_k(const float* __restrict__ x, const float* __restrict__ gates,
                      const float* __restrict__ W1, const float* __restrict__ b1,
                      const float* __restrict__ W2, const float* __restrict__ b2,
                      float* __restrict__ out, int n_tokens)
{
    __shared__ __align__(16) s16x4 w1lds[NE * 4 * 64];   // 16 KB: [e][n][lane]
    __shared__ __align__(16) s16x4 w2lds[NE * 4 * 64];   // 16 KB: [e][q][lane]
    __shared__ __align__(16) float b1_lds[NE * HID];     // 2 KB
    __shared__ __align__(16) float b2_lds[NE * EMB];     // 512 B
    __shared__ __align__(16) float wt_lds[4 * 8 * TPG];  // 8 KB: [wave][e][tok]

    const int tid = threadIdx.x;

    // ---- per-block: weights fp32->bf16 in per-lane fragment order ----
    // w1lds[(e*4+n)*64 + lane(cg,col)][j] = W1[e][4cg+j][16n+col]   (G1 A-frag, swapped)
    // w2lds[(e*4+q)*64 + lane(cg,col)][j] = W2[e][16q+4cg+j][col]   (G2 A-frag, swapped)
    for (int s = tid; s < NE * 4 * 64; s += 256) {
        const int e = s >> 8, nq = (s >> 6) & 3, l = s & 63;
        const int cc = l & 15, gg = (l >> 4) & 3;
        s16x4 t1, t2;
#pragma unroll
        for (int j = 0; j < 4; ++j) {
            t1[j] = f2bf(W1[(e * EMB + 4 * gg + j) * HID + 16 * nq + cc]);
            t2[j] = f2bf(W2[(e * HID + 16 * nq + 4 * gg + j) * EMB + cc]);
        }
        w1lds[s] = t1;
        w2lds[s] = t2;
    }
    for (int i = tid; i < NE * HID; i += 256) b1_lds[i] = b1[i];
    if (tid < NE * EMB) b2_lds[tid] = b2[tid];
    __syncthreads();

    const int lane = tid & 63;
    const int wid  = tid >> 6;
    const int col  = lane & 15;
    const int cg   = lane >> 4;
    float* wtw = wt_lds + wid * (NE * TPG);   // wave-private gate slab

    const int n_groups = n_tokens / TPG;
    for (int g = blockIdx.x * 4 + wid; g < n_groups; g += gridDim.x * 4) {
        const int tok0 = g * TPG;

        // stage this group's gates: lane loads its token's 8 gates, transposes to [e][tok]
        {
            const f32x4* gp = (const f32x4*)(gates + (size_t)(tok0 + lane) * NE);
            const f32x4 ga = gp[0], gb = gp[1];
#pragma unroll
            for (int e = 0; e < 4; ++e) wtw[e * TPG + lane] = ga[e];
#pragma unroll
            for (int e = 4; e < 8; ++e) wtw[e * TPG + lane] = gb[e - 4];
            // wave-private write->read; compiler inserts lgkmcnt, no barrier needed
        }

        // ---- one 16-token tile at a time: minimal live set ----
#pragma unroll 1
        for (int T = 0; T < 4; ++T) {
            const int tok = tok0 + 16 * T + col;
            // G1 B-frag: B[k=4cg+j][tok=col] = x[tok][4cg+j]
            const f32x4 xv = *(const f32x4*)(x + (size_t)tok * EMB + 4 * cg);
            s16x4 xb;
#pragma unroll
            for (int j = 0; j < 4; ++j) xb[j] = f2bf(xv[j]);

            // oacc init = Sum_e w_e * b2[e][4cg+r] (bias bypasses relu-weighting)
            f32x4 oacc = {0.f, 0.f, 0.f, 0.f};
#pragma unroll
            for (int e = 0; e < NE; ++e) {
                const float wv  = wtw[e * TPG + 16 * T + col];
                const f32x4 b2c = *(const f32x4*)(b2_lds + e * EMB + 4 * cg);
#pragma unroll
                for (int r = 0; r < 4; ++r) oacc[r] = fmaf(wv, b2c[r], oacc[r]);
            }

#pragma unroll 1
            for (int e = 0; e < NE; ++e) {
                const float wv = wtw[e * TPG + 16 * T + col];
                // G1: h^T tile n (lane: h[tok=col][hid=16n+4cg+r]), C-in = b1
                f32x4 h[4];
#pragma unroll
                for (int n = 0; n < 4; ++n) {
                    const s16x4 a1  = w1lds[(e * 4 + n) * 64 + lane];
                    const f32x4 b1c = *(const f32x4*)(b1_lds + e * HID + 16 * n + 4 * cg);
                    h[n] = __builtin_amdgcn_mfma_f32_16x16x16bf16_1k(a1, xb, b1c, 0, 0, 0);
                }
                // G2 swapped: eoT[emb][tok]; A = W2^T frag, B = w*relu(h); C chains q AND e
#pragma unroll
                for (int q = 0; q < 4; ++q) {
                    const s16x4 a2 = w2lds[(e * 4 + q) * 64 + lane];
                    s16x4 b;
#pragma unroll
                    for (int j = 0; j < 4; ++j) b[j] = f2bf(fmaxf(h[q][j], 0.f) * wv);
                    oacc = __builtin_amdgcn_mfma_f32_16x16x16bf16_1k(a2, b, oacc, 0, 0, 0);
                }
            }

            // lane owns token 16T+col, emb 4cg..4cg+3 -> wave stores 1 KB contiguous
            __builtin_nontemporal_store(oacc, (f32x4*)(out + (size_t)tok * EMB + 4 * cg));
        }
    }
}

// ============================================================================
// Fallback (ws too small): round-5 fused kernel, unchanged.
// ============================================================================
__global__ __launch_bounds__(512, 2)
void moe_fused(const float* __restrict__ x, const float* __restrict__ Wr,
               const float* __restrict__ br, const float* __restrict__ W1,
               const float* __restrict__ b1, const float* __restrict__ W2,
               const float* __restrict__ b2, float* __restrict__ out,
               int n_tokens)
{
    __shared__ __align__(16) s16x4 w1lds[NE * 4 * 64];
    __shared__ __align__(16) s16x4 w2lds[NE * 4 * 64];
    __shared__ __align__(16) float b1_lds[NE * HID];
    __shared__ __align__(16) float wr_lds[EMB * NE];
    __shared__ __align__(16) float br_lds[NE];
    __shared__ __align__(16) float b2_lds[NE * EMB];
    __shared__ __align__(16) float wt_lds[8 * NE * TPG];

    const int tid = threadIdx.x;
    for (int s = tid; s < NE * 4 * 64; s += 512) {
        const int e = s >> 8, nq = (s >> 6) & 3, l = s & 63;
        const int cc = l & 15, gg = (l >> 4) & 3;
        s16x4 t1, t2;
#pragma unroll
        for (int j = 0; j < 4; ++j) {
            t1[j] = f2bf(W1[(e * EMB + 4 * gg + j) * HID + 16 * nq + cc]);
            t2[j] = f2bf(W2[(e * HID + 16 * nq + 4 * gg + j) * EMB + cc]);
        }
        w1lds[s] = t1;
        w2lds[s] = t2;
    }
    for (int i = tid; i < NE * HID; i += 512) b1_lds[i] = b1[i];
    if (tid < EMB * NE) wr_lds[tid] = Wr[tid];
    if (tid < NE * EMB) b2_lds[tid] = b2[tid];
    if (tid < NE) br_lds[tid] = br[tid];
    __syncthreads();

    const int lane = tid & 63;
    const int wid  = tid >> 6;
    const int col  = lane & 15;
    const int cg   = lane >> 4;
    float* wt = wt_lds + wid * (NE * TPG);

    const int n_groups = n_tokens / TPG;
    for (int g = blockIdx.x * 8 + wid; g < n_groups; g += gridDim.x * 8) {
        const int tok0 = g * TPG;
        {
            float xk[EMB];
            const f32x4* xp = (const f32x4*)(x + (tok0 + lane) * EMB);
#pragma unroll
            for (int q4 = 0; q4 < 4; ++q4) {
                f32x4 v = xp[q4];
#pragma unroll
                for (int j = 0; j < 4; ++j) xk[q4 * 4 + j] = v[j];
            }
            float lg[NE];
#pragma unroll
            for (int e = 0; e < NE; ++e) lg[e] = br_lds[e];
#pragma unroll
            for (int k = 0; k < EMB; ++k) {
                const float xv = xk[k];
#pragma unroll
                for (int e = 0; e < NE; ++e) lg[e] = fmaf(xv, wr_lds[k * NE + e], lg[e]);
            }
            float m1 = -1e30f, m2 = -1e30f, m3 = -1e30f;
#pragma unroll
            for (int e = 0; e < NE; ++e) {
                const float v   = lg[e];
                const float hi  = fmaxf(m1, v), lo  = fminf(m1, v);
                const float hi2 = fmaxf(m2, lo), lo2 = fminf(m2, lo);
                m1 = hi; m2 = hi2; m3 = fmaxf(m3, lo2);
            }
            bool sel[NE];
            if (m2 - m3 < 1e-4f) {
                double dl[NE];
#pragma unroll
                for (int e = 0; e < NE; ++e) dl[e] = (double)br_lds[e];
#pragma unroll
                for (int k = 0; k < EMB; ++k) {
                    const double xv = (double)xk[k];
#pragma unroll
                    for (int e = 0; e < NE; ++e)
                        dl[e] = fma(xv, (double)wr_lds[k * NE + e], dl[e]);
                }
                double M1 = -1e300, M2 = -1e300;
#pragma unroll
                for (int e = 0; e < NE; ++e) {
                    const double v  = dl[e];
                    const double hi = fmax(M1, v);
                    M2 = fmax(M2, fmin(M1, v));
                    M1 = hi;
                }
#pragma unroll
                for (int e = 0; e < NE; ++e) sel[e] = (dl[e] >= M2);
            } else {
#pragma unroll
                for (int e = 0; e < NE; ++e) sel[e] = (lg[e] >= m2);
            }
            float w[NE], s = 0.f;
#pragma unroll
            for (int e = 0; e < NE; ++e) { w[e] = __expf(lg[e] - m1); s += w[e]; }
            const float inv = 1.0f / s;
#pragma unroll
            for (int e = 0; e < NE; ++e)
                wt[e * TPG + lane] = sel[e] ? w[e] * inv : 0.0f;
        }

#pragma unroll 1
        for (int T = 0; T < 4; ++T) {
            const int tok = tok0 + 16 * T + col;
            const f32x4 xv = *(const f32x4*)(x + tok * EMB + 4 * cg);
            s16x4 xb;
#pragma unroll
            for (int j = 0; j < 4; ++j) xb[j] = f2bf(xv[j]);

            f32x4 oacc = {0.f, 0.f, 0.f, 0.f};
#pragma unroll
            for (int e = 0; e < NE; ++e) {
                const float wv  = wt[e * TPG + 16 * T + col];
                const f32x4 b2c = *(const f32x4*)(b2_lds + e * EMB + 4 * cg);
#pragma unroll
                for (int r = 0; r < 4; ++r) oacc[r] = fmaf(wv, b2c[r], oacc[r]);
            }
#pragma unroll 1
            for (int e = 0; e < NE; ++e) {
                const float wv = wt[e * TPG + 16 * T + col];
                f32x4 h[4];
#pragma unroll
                for (int n = 0; n < 4; ++n) {
                    const s16x4 a1  = w1lds[(e * 4 + n) * 64 + lane];
                    const f32x4 b1c = *(const f32x4*)(b1_lds + e * HID + 16 * n + 4 * cg);
                    h[n] = __builtin_amdgcn_mfma_f32_16x16x16bf16_1k(a1, xb, b1c, 0, 0, 0);
                }
#pragma unroll
                for (int q = 0; q < 4; ++q) {
                    const s16x4 a2 = w2lds[(e * 4 + q) * 64 + lane];
                    s16x4 b;
#pragma unroll
                    for (int j = 0; j < 4; ++j) b[j] = f2bf(fmaxf(h[q][j], 0.f) * wv);
                    oacc = __builtin_amdgcn_mfma_f32_16x16x16bf16_1k(a2, b, oacc, 0, 0, 0);
                }
            }
            __builtin_nontemporal_store(oacc, (f32x4*)(out + tok * EMB + 4 * cg));
        }
    }
}

extern "C" void kernel_launch(void* const* d_in, const int* in_sizes, int n_in,
                              void* d_out, int out_size, void* d_ws, size_t ws_size,
                              hipStream_t stream) {
    const float* x  = (const float*)d_in[0];
    const float* Wr = (const float*)d_in[1];
    const float* br = (const float*)d_in[2];
    const float* W1 = (const float*)d_in[3];
    const float* b1 = (const float*)d_in[4];
    const float* W2 = (const float*)d_in[5];
    const float* b2 = (const float*)d_in[6];
    float* out = (float*)d_out;

    const int n_tokens = in_sizes[0] / EMB;   // 262144
    const size_t gates_bytes = (size_t)n_tokens * NE * sizeof(float);  // 8 MB

    if (ws_size >= gates_bytes) {
        float* gates = (float*)d_ws;
        hipLaunchKernelGGL(router_k, dim3(1024), dim3(256), 0, stream,
                           x, Wr, br, gates, n_tokens);
        hipLaunchKernelGGL(moe_k, dim3(1024), dim3(256), 0, stream,
                           x, gates, W1, b1, W2, b2, out, n_tokens);
    } else {
        hipLaunchKernelGGL(moe_fused, dim3(512), dim3(512), 0, stream,
                           x, Wr, br, W1, b1, W2, b2, out, n_tokens);
    }
}

// Round 7
// 42.001 us; speedup vs baseline: 5.3239x; 2.8830x over previous
//
#include <hip/hip_runtime.h>
#include <hip/hip_bf16.h>

#define EMB 16
#define HID 64
#define NE  8
#define TPG 64   // tokens per wave-group

typedef float  f32x4 __attribute__((ext_vector_type(4)));
typedef double f64x4 __attribute__((ext_vector_type(4)));
typedef short  s16x4 __attribute__((ext_vector_type(4)));

// fp32 -> bf16, round-to-nearest-even (no NaN in this workload)
__device__ __forceinline__ short f2bf(float f) {
    union { float f; unsigned u; } v; v.f = f;
    unsigned u = v.u;
    u += 0x7FFFu + ((u >> 16) & 1u);
    return (short)(u >> 16);
}

__device__ __forceinline__ f32x4 vfmaf(float s, f32x4 a, f32x4 c) {
    f32x4 r;
    r[0] = fmaf(s, a[0], c[0]); r[1] = fmaf(s, a[1], c[1]);
    r[2] = fmaf(s, a[2], c[2]); r[3] = fmaf(s, a[3], c[3]);
    return r;
}
__device__ __forceinline__ f64x4 vfmad(double s, f32x4 a, f64x4 c) {
    f64x4 r;
    r[0] = fma(s, (double)a[0], c[0]); r[1] = fma(s, (double)a[1], c[1]);
    r[2] = fma(s, (double)a[2], c[2]); r[3] = fma(s, (double)a[3], c[3]);
    return r;
}

// ============================================================================
// Kernel 1: router. One thread per token, ZERO arrays (everything static-indexed
// vectors / scalars / a bitmask), rescue is wave-uniform fp64 recompute.
// Round-6 evidence: the array+divergent-branch router emitted ~280 MB of HBM
// writes (scratch writeback) = 95 us. This version has nothing to spill.
// ============================================================================
__global__ __launch_bounds__(256, 2)
void router_k(const float* __restrict__ x, const float* __restrict__ Wr,
              const float* __restrict__ br, float* __restrict__ gates,
              int n_tokens)
{
    __shared__ float wr_lds[EMB * NE];
    __shared__ float br_lds[NE];
    const int tid = threadIdx.x;
    if (tid < EMB * NE) wr_lds[tid] = Wr[tid];
    if (tid < NE) br_lds[tid] = br[tid];
    __syncthreads();

    const int t = blockIdx.x * 256 + tid;
    if (t >= n_tokens) return;

    const f32x4* xp = (const f32x4*)(x + (size_t)t * EMB);
    const f32x4 x0 = xp[0], x1 = xp[1], x2 = xp[2], x3 = xp[3];

    // logits: experts 0-3 in lgA, 4-7 in lgB (static component access only)
    f32x4 lgA = *(const f32x4*)(br_lds + 0);
    f32x4 lgB = *(const f32x4*)(br_lds + 4);
#define RSTEP(K, XV) do { const float xv_ = (XV); \
        lgA = vfmaf(xv_, *(const f32x4*)(wr_lds + (K) * NE),     lgA); \
        lgB = vfmaf(xv_, *(const f32x4*)(wr_lds + (K) * NE + 4), lgB); } while (0)
    RSTEP(0,  x0[0]); RSTEP(1,  x0[1]); RSTEP(2,  x0[2]); RSTEP(3,  x0[3]);
    RSTEP(4,  x1[0]); RSTEP(5,  x1[1]); RSTEP(6,  x1[2]); RSTEP(7,  x1[3]);
    RSTEP(8,  x2[0]); RSTEP(9,  x2[1]); RSTEP(10, x2[2]); RSTEP(11, x2[3]);
    RSTEP(12, x3[0]); RSTEP(13, x3[1]); RSTEP(14, x3[2]); RSTEP(15, x3[3]);
#undef RSTEP

    // top-3 scan (m3 only gates the rescue)
    float m1 = -1e30f, m2 = -1e30f, m3 = -1e30f;
#define MSCAN(V) do { const float v_ = (V); \
        const float hi_ = fmaxf(m1, v_), lo_ = fminf(m1, v_); \
        const float hi2_ = fmaxf(m2, lo_), lo2_ = fminf(m2, lo_); \
        m1 = hi_; m2 = hi2_; m3 = fmaxf(m3, lo2_); } while (0)
    MSCAN(lgA[0]); MSCAN(lgA[1]); MSCAN(lgA[2]); MSCAN(lgA[3]);
    MSCAN(lgB[0]); MSCAN(lgB[1]); MSCAN(lgB[2]); MSCAN(lgB[3]);
#undef MSCAN

    // top-2 selection as a bitmask (no bool array)
    int sm = 0;
    sm |= (lgA[0] >= m2) << 0; sm |= (lgA[1] >= m2) << 1;
    sm |= (lgA[2] >= m2) << 2; sm |= (lgA[3] >= m2) << 3;
    sm |= (lgB[0] >= m2) << 4; sm |= (lgB[1] >= m2) << 5;
    sm |= (lgB[2] >= m2) << 6; sm |= (lgB[3] >= m2) << 7;

    // rescue: near-tie at the top-2 boundary -> whole wave redoes selection in
    // fp64 (wave-uniform branch, ~2.5% of waves; array-free vectors).
    if (__any(m2 - m3 < 1e-4f)) {
        f64x4 dA, dB;
        dA[0] = (double)br_lds[0]; dA[1] = (double)br_lds[1];
        dA[2] = (double)br_lds[2]; dA[3] = (double)br_lds[3];
        dB[0] = (double)br_lds[4]; dB[1] = (double)br_lds[5];
        dB[2] = (double)br_lds[6]; dB[3] = (double)br_lds[7];
#define DSTEP(K, XV) do { const double xv_ = (double)(XV); \
        dA = vfmad(xv_, *(const f32x4*)(wr_lds + (K) * NE),     dA); \
        dB = vfmad(xv_, *(const f32x4*)(wr_lds + (K) * NE + 4), dB); } while (0)
        DSTEP(0,  x0[0]); DSTEP(1,  x0[1]); DSTEP(2,  x0[2]); DSTEP(3,  x0[3]);
        DSTEP(4,  x1[0]); DSTEP(5,  x1[1]); DSTEP(6,  x1[2]); DSTEP(7,  x1[3]);
        DSTEP(8,  x2[0]); DSTEP(9,  x2[1]); DSTEP(10, x2[2]); DSTEP(11, x2[3]);
        DSTEP(12, x3[0]); DSTEP(13, x3[1]); DSTEP(14, x3[2]); DSTEP(15, x3[3]);
#undef DSTEP
        double M1 = -1e300, M2 = -1e300;
#define DSCAN(V) do { const double v_ = (V); \
        const double hi_ = fmax(M1, v_); M2 = fmax(M2, fmin(M1, v_)); M1 = hi_; } while (0)
        DSCAN(dA[0]); DSCAN(dA[1]); DSCAN(dA[2]); DSCAN(dA[3]);
        DSCAN(dB[0]); DSCAN(dB[1]); DSCAN(dB[2]); DSCAN(dB[3]);
#undef DSCAN
        sm = 0;
        sm |= (dA[0] >= M2) << 0; sm |= (dA[1] >= M2) << 1;
        sm |= (dA[2] >= M2) << 2; sm |= (dA[3] >= M2) << 3;
        sm |= (dB[0] >= M2) << 4; sm |= (dB[1] >= M2) << 5;
        sm |= (dB[2] >= M2) << 6; sm |= (dB[3] >= M2) << 7;
    }

    // softmax weights (fp32; continuous in logits, fp32 accuracy is ample)
    f32x4 gA, gB;
    gA[0] = __expf(lgA[0] - m1); gA[1] = __expf(lgA[1] - m1);
    gA[2] = __expf(lgA[2] - m1); gA[3] = __expf(lgA[3] - m1);
    gB[0] = __expf(lgB[0] - m1); gB[1] = __expf(lgB[1] - m1);
    gB[2] = __expf(lgB[2] - m1); gB[3] = __expf(lgB[3] - m1);
    const float s = gA[0] + gA[1] + gA[2] + gA[3] + gB[0] + gB[1] + gB[2] + gB[3];
    const float inv = 1.0f / s;
    gA[0] = (sm & 1)   ? gA[0] * inv : 0.f;  gA[1] = (sm & 2)   ? gA[1] * inv : 0.f;
    gA[2] = (sm & 4)   ? gA[2] * inv : 0.f;  gA[3] = (sm & 8)   ? gA[3] * inv : 0.f;
    gB[0] = (sm & 16)  ? gB[0] * inv : 0.f;  gB[1] = (sm & 32)  ? gB[1] * inv : 0.f;
    gB[2] = (sm & 64)  ? gB[2] * inv : 0.f;  gB[3] = (sm & 128) ? gB[3] * inv : 0.f;

    f32x4* gp = (f32x4*)(gates + (size_t)t * NE);
    gp[0] = gA;   // 32 B/token, wave-contiguous; L2-hot for moe_k
    gp[1] = gB;
}

// ============================================================================
// Kernel 2: MoE compute (unchanged from round 6 except launch_bounds to block
// the VGPR-64 clamp). Per wave: one 64-token group, 4 tiles of 16 tokens.
// ============================================================================
__global__ __launch_bounds__(256, 2)
void moe_k(const float* __restrict__ x, const float* __restrict__ gates,
           const float* __restrict__ W1, const float* __restrict__ b1,
           const float* __restrict__ W2, const float* __restrict__ b2,
           float* __restrict__ out, int n_tokens)
{
    __shared__ __align__(16) s16x4 w1lds[NE * 4 * 64];   // 16 KB: [e][n][lane]
    __shared__ __align__(16) s16x4 w2lds[NE * 4 * 64];   // 16 KB: [e][q][lane]
    __shared__ __align__(16) float b1_lds[NE * HID];     // 2 KB
    __shared__ __align__(16) float b2_lds[NE * EMB];     // 512 B
    __shared__ __align__(16) float wt_lds[4 * 8 * TPG];  // 8 KB: [wave][e][tok]

    const int tid = threadIdx.x;

    // ---- per-block: weights fp32->bf16 in per-lane fragment order ----
    // w1lds[(e*4+n)*64 + lane(cg,col)][j] = W1[e][4cg+j][16n+col]   (G1 A-frag, swapped)
    // w2lds[(e*4+q)*64 + lane(cg,col)][j] = W2[e][16q+4cg+j][col]   (G2 A-frag, swapped)
    for (int s = tid; s < NE * 4 * 64; s += 256) {
        const int e = s >> 8, nq = (s >> 6) & 3, l = s & 63;
        const int cc = l & 15, gg = (l >> 4) & 3;
        s16x4 t1, t2;
#pragma unroll
        for (int j = 0; j < 4; ++j) {
            t1[j] = f2bf(W1[(e * EMB + 4 * gg + j) * HID + 16 * nq + cc]);
            t2[j] = f2bf(W2[(e * HID + 16 * nq + 4 * gg + j) * EMB + cc]);
        }
        w1lds[s] = t1;
        w2lds[s] = t2;
    }
    for (int i = tid; i < NE * HID; i += 256) b1_lds[i] = b1[i];
    if (tid < NE * EMB) b2_lds[tid] = b2[tid];
    __syncthreads();

    const int lane = tid & 63;
    const int wid  = tid >> 6;
    const int col  = lane & 15;
    const int cg   = lane >> 4;
    float* wtw = wt_lds + wid * (NE * TPG);   // wave-private gate slab

    const int n_groups = n_tokens / TPG;
    for (int g = blockIdx.x * 4 + wid; g < n_groups; g += gridDim.x * 4) {
        const int tok0 = g * TPG;

        // stage this group's gates: lane loads its token's 8 gates, transposes to [e][tok]
        {
            const f32x4* gp = (const f32x4*)(gates + (size_t)(tok0 + lane) * NE);
            const f32x4 ga = gp[0], gb = gp[1];
#pragma unroll
            for (int e = 0; e < 4; ++e) wtw[e * TPG + lane] = ga[e];
#pragma unroll
            for (int e = 4; e < 8; ++e) wtw[e * TPG + lane] = gb[e - 4];
            // wave-private write->read; compiler inserts lgkmcnt, no barrier needed
        }

        // ---- one 16-token tile at a time: minimal live set ----
#pragma unroll 1
        for (int T = 0; T < 4; ++T) {
            const int tok = tok0 + 16 * T + col;
            // G1 B-frag: B[k=4cg+j][tok=col] = x[tok][4cg+j]
            const f32x4 xv = *(const f32x4*)(x + (size_t)tok * EMB + 4 * cg);
            s16x4 xb;
#pragma unroll
            for (int j = 0; j < 4; ++j) xb[j] = f2bf(xv[j]);

            // oacc init = Sum_e w_e * b2[e][4cg+r] (bias bypasses relu-weighting)
            f32x4 oacc = {0.f, 0.f, 0.f, 0.f};
#pragma unroll
            for (int e = 0; e < NE; ++e) {
                const float wv  = wtw[e * TPG + 16 * T + col];
                const f32x4 b2c = *(const f32x4*)(b2_lds + e * EMB + 4 * cg);
#pragma unroll
                for (int r = 0; r < 4; ++r) oacc[r] = fmaf(wv, b2c[r], oacc[r]);
            }

#pragma unroll 1
            for (int e = 0; e < NE; ++e) {
                const float wv = wtw[e * TPG + 16 * T + col];
                // G1: h^T tile n (lane: h[tok=col][hid=16n+4cg+r]), C-in = b1
                f32x4 h[4];
#pragma unroll
                for (int n = 0; n < 4; ++n) {
                    const s16x4 a1  = w1lds[(e * 4 + n) * 64 + lane];
                    const f32x4 b1c = *(const f32x4*)(b1_lds + e * HID + 16 * n + 4 * cg);
                    h[n] = __builtin_amdgcn_mfma_f32_16x16x16bf16_1k(a1, xb, b1c, 0, 0, 0);
                }
                // G2 swapped: eoT[emb][tok]; A = W2^T frag, B = w*relu(h); C chains q AND e
#pragma unroll
                for (int q = 0; q < 4; ++q) {
                    const s16x4 a2 = w2lds[(e * 4 + q) * 64 + lane];
                    s16x4 b;
#pragma unroll
                    for (int j = 0; j < 4; ++j) b[j] = f2bf(fmaxf(h[q][j], 0.f) * wv);
                    oacc = __builtin_amdgcn_mfma_f32_16x16x16bf16_1k(a2, b, oacc, 0, 0, 0);
                }
            }

            // lane owns token 16T+col, emb 4cg..4cg+3 -> wave stores 1 KB contiguous
            __builtin_nontemporal_store(oacc, (f32x4*)(out + (size_t)tok * EMB + 4 * cg));
        }
    }
}

// ============================================================================
// Fallback (ws too small): round-5 fused kernel, unchanged.
// ============================================================================
__global__ __launch_bounds__(512, 2)
void moe_fused(const float* __restrict__ x, const float* __restrict__ Wr,
               const float* __restrict__ br, const float* __restrict__ W1,
               const float* __restrict__ b1, const float* __restrict__ W2,
               const float* __restrict__ b2, float* __restrict__ out,
               int n_tokens)
{
    __shared__ __align__(16) s16x4 w1lds[NE * 4 * 64];
    __shared__ __align__(16) s16x4 w2lds[NE * 4 * 64];
    __shared__ __align__(16) float b1_lds[NE * HID];
    __shared__ __align__(16) float wr_lds[EMB * NE];
    __shared__ __align__(16) float br_lds[NE];
    __shared__ __align__(16) float b2_lds[NE * EMB];
    __shared__ __align__(16) float wt_lds[8 * NE * TPG];

    const int tid = threadIdx.x;
    for (int s = tid; s < NE * 4 * 64; s += 512) {
        const int e = s >> 8, nq = (s >> 6) & 3, l = s & 63;
        const int cc = l & 15, gg = (l >> 4) & 3;
        s16x4 t1, t2;
#pragma unroll
        for (int j = 0; j < 4; ++j) {
            t1[j] = f2bf(W1[(e * EMB + 4 * gg + j) * HID + 16 * nq + cc]);
            t2[j] = f2bf(W2[(e * HID + 16 * nq + 4 * gg + j) * EMB + cc]);
        }
        w1lds[s] = t1;
        w2lds[s] = t2;
    }
    for (int i = tid; i < NE * HID; i += 512) b1_lds[i] = b1[i];
    if (tid < EMB * NE) wr_lds[tid] = Wr[tid];
    if (tid < NE * EMB) b2_lds[tid] = b2[tid];
    if (tid < NE) br_lds[tid] = br[tid];
    __syncthreads();

    const int lane = tid & 63;
    const int wid  = tid >> 6;
    const int col  = lane & 15;
    const int cg   = lane >> 4;
    float* wt = wt_lds + wid * (NE * TPG);

    const int n_groups = n_tokens / TPG;
    for (int g = blockIdx.x * 8 + wid; g < n_groups; g += gridDim.x * 8) {
        const int tok0 = g * TPG;
        {
            float xk[EMB];
            const f32x4* xp = (const f32x4*)(x + (tok0 + lane) * EMB);
#pragma unroll
            for (int q4 = 0; q4 < 4; ++q4) {
                f32x4 v = xp[q4];
#pragma unroll
                for (int j = 0; j < 4; ++j) xk[q4 * 4 + j] = v[j];
            }
            float lg[NE];
#pragma unroll
            for (int e = 0; e < NE; ++e) lg[e] = br_lds[e];
#pragma unroll
            for (int k = 0; k < EMB; ++k) {
                const float xv = xk[k];
#pragma unroll
                for (int e = 0; e < NE; ++e) lg[e] = fmaf(xv, wr_lds[k * NE + e], lg[e]);
            }
            float m1 = -1e30f, m2 = -1e30f, m3 = -1e30f;
#pragma unroll
            for (int e = 0; e < NE; ++e) {
                const float v   = lg[e];
                const float hi  = fmaxf(m1, v), lo  = fminf(m1, v);
                const float hi2 = fmaxf(m2, lo), lo2 = fminf(m2, lo);
                m1 = hi; m2 = hi2; m3 = fmaxf(m3, lo2);
            }
            bool sel[NE];
            if (m2 - m3 < 1e-4f) {
                double dl[NE];
#pragma unroll
                for (int e = 0; e < NE; ++e) dl[e] = (double)br_lds[e];
#pragma unroll
                for (int k = 0; k < EMB; ++k) {
                    const double xv = (double)xk[k];
#pragma unroll
                    for (int e = 0; e < NE; ++e)
                        dl[e] = fma(xv, (double)wr_lds[k * NE + e], dl[e]);
                }
                double M1 = -1e300, M2 = -1e300;
#pragma unroll
                for (int e = 0; e < NE; ++e) {
                    const double v  = dl[e];
                    const double hi = fmax(M1, v);
                    M2 = fmax(M2, fmin(M1, v));
                    M1 = hi;
                }
#pragma unroll
                for (int e = 0; e < NE; ++e) sel[e] = (dl[e] >= M2);
            } else {
#pragma unroll
                for (int e = 0; e < NE; ++e) sel[e] = (lg[e] >= m2);
            }
            float w[NE], s = 0.f;
#pragma unroll
            for (int e = 0; e < NE; ++e) { w[e] = __expf(lg[e] - m1); s += w[e]; }
            const float inv = 1.0f / s;
#pragma unroll
            for (int e = 0; e < NE; ++e)
                wt[e * TPG + lane] = sel[e] ? w[e] * inv : 0.0f;
        }

#pragma unroll 1
        for (int T = 0; T < 4; ++T) {
            const int tok = tok0 + 16 * T + col;
            const f32x4 xv = *(const f32x4*)(x + tok * EMB + 4 * cg);
            s16x4 xb;
#pragma unroll
            for (int j = 0; j < 4; ++j) xb[j] = f2bf(xv[j]);

            f32x4 oacc = {0.f, 0.f, 0.f, 0.f};
#pragma unroll
            for (int e = 0; e < NE; ++e) {
                const float wv  = wt[e * TPG + 16 * T + col];
                const f32x4 b2c = *(const f32x4*)(b2_lds + e * EMB + 4 * cg);
#pragma unroll
                for (int r = 0; r < 4; ++r) oacc[r] = fmaf(wv, b2c[r], oacc[r]);
            }
#pragma unroll 1
            for (int e = 0; e < NE; ++e) {
                const float wv = wt[e * TPG + 16 * T + col];
                f32x4 h[4];
#pragma unroll
                for (int n = 0; n < 4; ++n) {
                    const s16x4 a1  = w1lds[(e * 4 + n) * 64 + lane];
                    const f32x4 b1c = *(const f32x4*)(b1_lds + e * HID + 16 * n + 4 * cg);
                    h[n] = __builtin_amdgcn_mfma_f32_16x16x16bf16_1k(a1, xb, b1c, 0, 0, 0);
                }
#pragma unroll
                for (int q = 0; q < 4; ++q) {
                    const s16x4 a2 = w2lds[(e * 4 + q) * 64 + lane];
                    s16x4 b;
#pragma unroll
                    for (int j = 0; j < 4; ++j) b[j] = f2bf(fmaxf(h[q][j], 0.f) * wv);
                    oacc = __builtin_amdgcn_mfma_f32_16x16x16bf16_1k(a2, b, oacc, 0, 0, 0);
                }
            }
            __builtin_nontemporal_store(oacc, (f32x4*)(out + tok * EMB + 4 * cg));
        }
    }
}

extern "C" void kernel_launch(void* const* d_in, const int* in_sizes, int n_in,
                              void* d_out, int out_size, void* d_ws, size_t ws_size,
                              hipStream_t stream) {
    const float* x  = (const float*)d_in[0];
    const float* Wr = (const float*)d_in[1];
    const float* br = (const float*)d_in[2];
    const float* W1 = (const float*)d_in[3];
    const float* b1 = (const float*)d_in[4];
    const float* W2 = (const float*)d_in[5];
    const float* b2 = (const float*)d_in[6];
    float* out = (float*)d_out;

    const int n_tokens = in_sizes[0] / EMB;   // 262144
    const size_t gates_bytes = (size_t)n_tokens * NE * sizeof(float);  // 8 MB

    if (ws_size >= gates_bytes) {
        float* gates = (float*)d_ws;
        hipLaunchKernelGGL(router_k, dim3((n_tokens + 255) / 256), dim3(256), 0, stream,
                           x, Wr, br, gates, n_tokens);
        hipLaunchKernelGGL(moe_k, dim3(1024), dim3(256), 0, stream,
                           x, gates, W1, b1, W2, b2, out, n_tokens);
    } else {
        hipLaunchKernelGGL(moe_fused, dim3(512), dim3(512), 0, stream,
                           x, Wr, br, W1, b1, W2, b2, out, n_tokens);
    }
}